// Round 3
// baseline (189.056 us; speedup 1.0000x reference)
//
#include <hip/hip_runtime.h>
#include <hip/hip_bf16.h>
#include <math.h>

#define NA 2048   // agents (2^11)
#define TT 20     // timesteps
#define KK 32     // neighbors
#define CC 32     // in channels
#define OO 64     // out channels / hidden
#define GG 256    // 4*OO gates
#define SW 88     // feat_sh row stride in shorts: 176B = 16B-aligned, 2-way banks

typedef __attribute__((ext_vector_type(8))) short short8;
typedef __attribute__((ext_vector_type(4))) float float4v;

__device__ __forceinline__ float fast_rcp(float x) {
    return __builtin_amdgcn_rcpf(x);
}
__device__ __forceinline__ float sigm(float x) {
    return fast_rcp(1.f + __expf(-x));
}
__device__ __forceinline__ float tanh_fast(float x) {
    return 1.f - 2.f * fast_rcp(1.f + __expf(2.f * x));
}
__device__ __forceinline__ short f2bs(float f) {
    __hip_bfloat16 h = __float2bfloat16(f);
    short s;
    __builtin_memcpy(&s, &h, 2);
    return s;
}

// P[t][n][o] = sum_c x[n][t][c] * conv_w[o][c].  Lane = o, weights in regs.
__global__ __launch_bounds__(256) void proj_kernel(
    const float* __restrict__ x, const float* __restrict__ conv_w,
    float* __restrict__ P)
{
    const int lane = threadIdx.x & 63;
    const int wv = threadIdx.x >> 6;
    float w[CC];
    #pragma unroll
    for (int c = 0; c < CC; c += 4) {
        float4 v = *(const float4*)(conv_w + lane * CC + c);
        w[c] = v.x; w[c + 1] = v.y; w[c + 2] = v.z; w[c + 3] = v.w;
    }
    const int rbase = blockIdx.x * 16 + wv * 4;
    #pragma unroll
    for (int i = 0; i < 4; ++i) {
        int r = rbase + i;                    // r = n*TT + t (x row order)
        const float* xr = x + (size_t)r * CC;
        float a0 = 0.f, a1 = 0.f;
        #pragma unroll
        for (int c = 0; c < CC; c += 8) {
            float4 v = *(const float4*)(xr + c);
            float4 u = *(const float4*)(xr + c + 4);
            a0 = fmaf(v.x, w[c], a0);     a0 = fmaf(v.y, w[c + 1], a0);
            a0 = fmaf(v.z, w[c + 2], a0); a0 = fmaf(v.w, w[c + 3], a0);
            a1 = fmaf(u.x, w[c + 4], a1); a1 = fmaf(u.y, w[c + 5], a1);
            a1 = fmaf(u.z, w[c + 6], a1); a1 = fmaf(u.w, w[c + 7], a1);
        }
        int n = r / TT;
        int t = r - n * TT;
        P[(((size_t)t << 11) + n) * OO + lane] = a0 + a1;
    }
}

// Gather-max + gate matmul via MFMA.
// Block owns 16 rows (one t-slab segment). XCD-swizzled so each XCD keeps
// ~4 P-slabs hot in its private L2 (fixes the 63MB over-fetch).
// feat tile (16x64) staged bf16 in LDS; w_ih B-fragments live in VGPRs
// (global w_ih is L2-hot); gates computed by 8 MFMA per wave -> no LDS-port
// saturation (R2 was bound on 10k broadcast ds_read_b128 per CU).
// gx stored permuted: j' = oo*4 + gate, row(j') = (j'&3)*64 + (j'>>2).
__global__ __launch_bounds__(256) void gatemm_kernel(
    const float* __restrict__ P, const int* __restrict__ A,
    const float* __restrict__ conv_b, const float* __restrict__ w_ih,
    const float* __restrict__ b_ih, const float* __restrict__ b_hh,
    __hip_bfloat16* __restrict__ gx)
{
    const int tid = threadIdx.x;
    const int lane = tid & 63;
    const int wv = tid >> 6;
    const int l15 = lane & 15;
    const int q = lane >> 4;

    // XCD swizzle: blocks b with b%8==x go to XCD x (heuristic); give each
    // XCD a contiguous chunk-range so it touches ~4 of the 20 t-slabs.
    const int bs = (blockIdx.x & 7) * 320 + (blockIdx.x >> 3);
    const int r0 = bs << 4;                  // first row, r = t*NA + n
    const int t = r0 >> 11;
    const int n0 = r0 & (NA - 1);
    const float* Pt = P + ((size_t)t << 17); // t*NA*OO

    // B fragments: lane holds B[k = ks*32 + q*8 + j][n' = wv*64 + tt*16 + l15]
    // where B[k][n'] = w_ih[row(n')][k].
    short8 bfrag[4][2];
    #pragma unroll
    for (int tt = 0; tt < 4; ++tt) {
        int np = wv * 64 + tt * 16 + l15;
        int row = ((np & 3) << 6) + (np >> 2);
        #pragma unroll
        for (int ks = 0; ks < 2; ++ks) {
            int k0 = ks * 32 + q * 8;
            float4 w0 = *(const float4*)(w_ih + (size_t)row * OO + k0);
            float4 w1 = *(const float4*)(w_ih + (size_t)row * OO + k0 + 4);
            short8 bf;
            bf[0] = f2bs(w0.x); bf[1] = f2bs(w0.y);
            bf[2] = f2bs(w0.z); bf[3] = f2bs(w0.w);
            bf[4] = f2bs(w1.x); bf[5] = f2bs(w1.y);
            bf[6] = f2bs(w1.z); bf[7] = f2bs(w1.w);
            bfrag[tt][ks] = bf;
        }
    }

    __shared__ float bias_sh[GG];
    __shared__ __align__(16) short feat_sh[16 * SW];

    // bias for permuted column n' = tid (conv_b folded through w_ih)
    {
        int row = ((tid & 3) << 6) + (tid >> 2);
        float bj = b_ih[row] + b_hh[row];
        #pragma unroll
        for (int o = 0; o < OO; o += 4) {
            float4 cb = *(const float4*)(conv_b + o);
            float4 wr = *(const float4*)(w_ih + (size_t)row * OO + o);
            bj = fmaf(cb.x, wr.x, bj); bj = fmaf(cb.y, wr.y, bj);
            bj = fmaf(cb.z, wr.z, bj); bj = fmaf(cb.w, wr.w, bj);
        }
        bias_sh[tid] = bj;
    }

    // Gather-max: wave wv produces feat rows m = wv*4 .. wv*4+3
    #pragma unroll
    for (int i = 0; i < 4; ++i) {
        const int m = wv * 4 + i;
        const int r = r0 + m;
        const int n = n0 + m;
        int vA = A[((size_t)r << 5) + (lane & 31)];
        float p0 = -INFINITY, p1 = -INFINITY, p2 = -INFINITY, p3 = -INFINITY;
        #pragma unroll
        for (int k = 0; k < KK; k += 4) {
            int i0 = __builtin_amdgcn_readlane(vA, k);
            int i1 = __builtin_amdgcn_readlane(vA, k + 1);
            int i2 = __builtin_amdgcn_readlane(vA, k + 2);
            int i3 = __builtin_amdgcn_readlane(vA, k + 3);
            p0 = fmaxf(p0, Pt[((size_t)i0 << 6) + lane]);
            p1 = fmaxf(p1, Pt[((size_t)i1 << 6) + lane]);
            p2 = fmaxf(p2, Pt[((size_t)i2 << 6) + lane]);
            p3 = fmaxf(p3, Pt[((size_t)i3 << 6) + lane]);
        }
        float pm = fmaxf(fmaxf(p0, p1), fmaxf(p2, p3));
        feat_sh[m * SW + lane] = f2bs(pm - Pt[((size_t)n << 6) + lane]);
    }
    __syncthreads();

    // MFMA: D[16 rows][n' slice of 64] per wave, K=64 in 2 steps.
    float4v acc[4] = {{0.f, 0.f, 0.f, 0.f}, {0.f, 0.f, 0.f, 0.f},
                      {0.f, 0.f, 0.f, 0.f}, {0.f, 0.f, 0.f, 0.f}};
    #pragma unroll
    for (int ks = 0; ks < 2; ++ks) {
        short8 af = *(const short8*)(&feat_sh[l15 * SW + ks * 32 + q * 8]);
        #pragma unroll
        for (int tt = 0; tt < 4; ++tt)
            acc[tt] = __builtin_amdgcn_mfma_f32_16x16x32_bf16(
                af, bfrag[tt][ks], acc[tt], 0, 0, 0);
    }

    // Epilogue: + bias, store bf16.  D mapping: m = q*4 + reg, n' = col.
    #pragma unroll
    for (int tt = 0; tt < 4; ++tt) {
        int np = wv * 64 + tt * 16 + l15;
        float bv = bias_sh[np];
        #pragma unroll
        for (int rg = 0; rg < 4; ++rg) {
            int m = q * 4 + rg;
            gx[((size_t)(r0 + m) << 8) + np] = __float2bfloat16(acc[tt][rg] + bv);
        }
    }
}

// Serial recurrence: g = gx + h @ w_hh^T, pointwise LSTM cell.
// 2 agents/block, gsh double-buffered (1 barrier/t), h per-wave-private,
// 4 independent fma chains per agent to cut the critical path.
__global__ __launch_bounds__(256) void lstm_kernel(
    const __hip_bfloat16* __restrict__ gx, const float* __restrict__ w_hh,
    float* __restrict__ out)
{
    const int tid = threadIdx.x;
    const int lane = tid & 63;
    const int wv = tid >> 6;
    const int gate = tid & 3;
    const int oo = tid >> 2;
    const int row = gate * OO + oo;
    const int a0 = blockIdx.x * 2;

    float whh[OO];
    #pragma unroll
    for (int o = 0; o < OO; o += 4) {
        float4 v = *(const float4*)(w_hh + (size_t)row * OO + o);
        whh[o] = v.x; whh[o + 1] = v.y; whh[o + 2] = v.z; whh[o + 3] = v.w;
    }

    __shared__ float gsh[2][2][GG];
    __shared__ float hsh[4][2][OO];
    hsh[wv][0][lane] = 0.f;
    hsh[wv][1][lane] = 0.f;
    float c0 = 0.f, c1 = 0.f;
    float g0 = __bfloat162float(gx[((size_t)a0 << 8) + tid]);
    float g1 = __bfloat162float(gx[((size_t)(a0 + 1) << 8) + tid]);
    int buf = 0;

    for (int t = 0; t < TT; ++t) {
        float s0[4] = {g0, 0.f, 0.f, 0.f};
        float s1[4] = {g1, 0.f, 0.f, 0.f};
        #pragma unroll
        for (int o = 0; o < OO; o += 4) {
            const int j = (o >> 2) & 3;
            float4 h0 = *(const float4*)&hsh[wv][0][o];
            float4 h1 = *(const float4*)&hsh[wv][1][o];
            s0[j] = fmaf(h0.x, whh[o], s0[j]);
            s0[j] = fmaf(h0.y, whh[o + 1], s0[j]);
            s0[j] = fmaf(h0.z, whh[o + 2], s0[j]);
            s0[j] = fmaf(h0.w, whh[o + 3], s0[j]);
            s1[j] = fmaf(h1.x, whh[o], s1[j]);
            s1[j] = fmaf(h1.y, whh[o + 1], s1[j]);
            s1[j] = fmaf(h1.z, whh[o + 2], s1[j]);
            s1[j] = fmaf(h1.w, whh[o + 3], s1[j]);
        }
        gsh[buf][0][tid] = (s0[0] + s0[1]) + (s0[2] + s0[3]);
        gsh[buf][1][tid] = (s1[0] + s1[1]) + (s1[2] + s1[3]);
        __syncthreads();

        // prefetch next timestep's gx while gsh settles
        int tn = (t + 1 < TT) ? t + 1 : t;
        g0 = __bfloat162float(gx[(((size_t)tn << 11) + a0) * GG + tid]);
        g1 = __bfloat162float(gx[(((size_t)tn << 11) + a0 + 1) * GG + tid]);

        // pointwise cell update, redundant per wave; layout j' = o*4+gate
        float4 q0 = *(const float4*)&gsh[buf][0][lane << 2];
        float4 q1 = *(const float4*)&gsh[buf][1][lane << 2];
        float i0 = sigm(q0.x), f0 = sigm(q0.y);
        float z0 = tanh_fast(q0.z), o0 = sigm(q0.w);
        c0 = fmaf(f0, c0, i0 * z0);
        float h0v = o0 * tanh_fast(c0);
        float i1 = sigm(q1.x), f1 = sigm(q1.y);
        float z1 = tanh_fast(q1.z), o1 = sigm(q1.w);
        c1 = fmaf(f1, c1, i1 * z1);
        float h1v = o1 * tanh_fast(c1);
        hsh[wv][0][lane] = h0v;   // own-wave write; in-order DS, no barrier
        hsh[wv][1][lane] = h1v;

        if (wv == 0) {
            out[((size_t)a0 * TT + t) * OO + lane] = h0v;
            out[((size_t)(a0 + 1) * TT + t) * OO + lane] = h1v;
            if (t == TT - 1) {
                size_t hb = (size_t)NA * TT * OO;
                out[hb + (size_t)a0 * OO + lane] = h0v;
                out[hb + (size_t)(a0 + 1) * OO + lane] = h1v;
                out[hb + (size_t)NA * OO + (size_t)a0 * OO + lane] = c0;
                out[hb + (size_t)NA * OO + (size_t)(a0 + 1) * OO + lane] = c1;
            }
        }
        buf ^= 1;
    }
}

extern "C" void kernel_launch(void* const* d_in, const int* in_sizes, int n_in,
                              void* d_out, int out_size, void* d_ws, size_t ws_size,
                              hipStream_t stream) {
    const float* x      = (const float*)d_in[0];
    const int*   A      = (const int*)  d_in[1];
    const float* conv_w = (const float*)d_in[2];
    const float* conv_b = (const float*)d_in[3];
    const float* w_ih   = (const float*)d_in[4];
    const float* w_hh   = (const float*)d_in[5];
    const float* b_ih   = (const float*)d_in[6];
    const float* b_hh   = (const float*)d_in[7];
    float* out = (float*)d_out;

    float* P = (float*)d_ws;                              // 10.5 MB
    __hip_bfloat16* gx =
        (__hip_bfloat16*)((char*)d_ws + (size_t)TT * NA * OO * sizeof(float));  // 21 MB

    hipLaunchKernelGGL(proj_kernel, dim3(NA * TT / 16), dim3(256), 0, stream,
                       x, conv_w, P);
    hipLaunchKernelGGL(gatemm_kernel, dim3(NA * TT / 16), dim3(256), 0, stream,
                       P, A, conv_b, w_ih, b_ih, b_hh, gx);
    hipLaunchKernelGGL(lstm_kernel, dim3(NA / 2), dim3(256), 0, stream,
                       gx, w_hh, out);
}

// Round 4
// 163.052 us; speedup vs baseline: 1.1595x; 1.1595x over previous
//
#include <hip/hip_runtime.h>
#include <hip/hip_bf16.h>
#include <math.h>

#define NA 2048   // agents (2^11)
#define TT 20     // timesteps
#define KK 32     // neighbors
#define CC 32     // in channels
#define OO 64     // out channels / hidden
#define GG 256    // 4*OO gates
#define SW 88     // feat_sh row stride in shorts

typedef __attribute__((ext_vector_type(8))) short short8;
typedef __attribute__((ext_vector_type(4))) float float4v;

__device__ __forceinline__ float fast_rcp(float x) {
    return __builtin_amdgcn_rcpf(x);
}
__device__ __forceinline__ float sigm(float x) {
    return fast_rcp(1.f + __expf(-x));
}
__device__ __forceinline__ float tanh_fast(float x) {
    return 1.f - 2.f * fast_rcp(1.f + __expf(2.f * x));
}
__device__ __forceinline__ short f2bs(float f) {
    __hip_bfloat16 h = __float2bfloat16(f);
    short s;
    __builtin_memcpy(&s, &h, 2);
    return s;
}
__device__ __forceinline__ float bf_lo(unsigned u) {
    return __uint_as_float(u << 16);
}
__device__ __forceinline__ float bf_hi(unsigned u) {
    return __uint_as_float(u & 0xffff0000u);
}
__device__ __forceinline__ unsigned pack2(float a, float b) {
    return (unsigned)(unsigned short)f2bs(a) | ((unsigned)(unsigned short)f2bs(b) << 16);
}

// P[t][n][o] = sum_c x[n][t][c] * conv_w[o][c], stored bf16 (128B rows ->
// one dwordx2 gather covers 4 rows downstream).
__global__ __launch_bounds__(256) void proj_kernel(
    const float* __restrict__ x, const float* __restrict__ conv_w,
    __hip_bfloat16* __restrict__ P)
{
    const int lane = threadIdx.x & 63;
    const int wv = threadIdx.x >> 6;
    float w[CC];
    #pragma unroll
    for (int c = 0; c < CC; c += 4) {
        float4 v = *(const float4*)(conv_w + lane * CC + c);
        w[c] = v.x; w[c + 1] = v.y; w[c + 2] = v.z; w[c + 3] = v.w;
    }
    const int rbase = blockIdx.x * 16 + wv * 4;
    #pragma unroll
    for (int i = 0; i < 4; ++i) {
        int r = rbase + i;                    // r = n*TT + t (x row order)
        const float* xr = x + (size_t)r * CC;
        float a0 = 0.f, a1 = 0.f;
        #pragma unroll
        for (int c = 0; c < CC; c += 8) {
            float4 v = *(const float4*)(xr + c);
            float4 u = *(const float4*)(xr + c + 4);
            a0 = fmaf(v.x, w[c], a0);     a0 = fmaf(v.y, w[c + 1], a0);
            a0 = fmaf(v.z, w[c + 2], a0); a0 = fmaf(v.w, w[c + 3], a0);
            a1 = fmaf(u.x, w[c + 4], a1); a1 = fmaf(u.y, w[c + 5], a1);
            a1 = fmaf(u.z, w[c + 6], a1); a1 = fmaf(u.w, w[c + 7], a1);
        }
        int n = r / TT;
        int t = r - n * TT;
        P[(((size_t)t << 11) + n) * OO + lane] = __float2bfloat16(a0 + a1);
    }
}

// Gather-max + gate matmul (MFMA). P is bf16: one dwordx2 per lane covers
// 4 rows/wave-load (quad = lane>>4 selects row, l15*8B = 4 channels).
// Loads batched 16-deep for ILP (R3 was latency-bound at ~1 load/30cyc/CU
// with 64 VGPRs). XCD swizzle keeps each t-slab on one XCD's L2.
// gx[r][j] standard layout j = gate*64+ch, bf16, full bias folded in.
__global__ __launch_bounds__(256, 4) void gatemm_kernel(
    const __hip_bfloat16* __restrict__ P, const int* __restrict__ A,
    const float* __restrict__ conv_b, const float* __restrict__ w_ih,
    const float* __restrict__ b_ih, const float* __restrict__ b_hh,
    __hip_bfloat16* __restrict__ gx)
{
    const int tid = threadIdx.x;
    const int lane = tid & 63;
    const int wv = tid >> 6;
    const int l15 = lane & 15;
    const int q = lane >> 4;          // quad: gather row select / MFMA k-group

    const int bs = (blockIdx.x & 7) * 320 + (blockIdx.x >> 3);
    const int r0 = bs << 4;                  // first row, r = t*NA + n
    const int t = r0 >> 11;
    const int n0 = r0 & (NA - 1);
    const unsigned short* Pb = (const unsigned short*)P + ((size_t)t << 17);

    __shared__ float bias_sh[GG];
    __shared__ __align__(16) unsigned short feat_sh[16 * SW];

    // bias for gate-row tid (conv_b folded through w_ih)
    {
        float bj = b_ih[tid] + b_hh[tid];
        #pragma unroll
        for (int o = 0; o < OO; o += 4) {
            float4 cb = *(const float4*)(conv_b + o);
            float4 wr = *(const float4*)(w_ih + (size_t)tid * OO + o);
            bj = fmaf(cb.x, wr.x, bj); bj = fmaf(cb.y, wr.y, bj);
            bj = fmaf(cb.z, wr.z, bj); bj = fmaf(cb.w, wr.w, bj);
        }
        bias_sh[tid] = bj;
    }

    // ---- gather-max: wave owns rows rbase..rbase+3, quad q = row, l15 = 4ch
    const int rbase = r0 + wv * 4;
    const int vA01 = A[((size_t)rbase << 5) + lane];        // rows +0,+1
    const int vA23 = A[((size_t)(rbase + 2) << 5) + lane];  // rows +2,+3

    float m0 = -INFINITY, m1 = -INFINITY, m2 = -INFINITY, m3 = -INFINITY;
    #pragma unroll
    for (int half = 0; half < 2; ++half) {
        int idxv[16];
        #pragma unroll
        for (int kk = 0; kk < 16; ++kk) {
            int k = half * 16 + kk;
            int i0 = __builtin_amdgcn_readlane(vA01, k);
            int i1 = __builtin_amdgcn_readlane(vA01, k + 32);
            int i2 = __builtin_amdgcn_readlane(vA23, k);
            int i3 = __builtin_amdgcn_readlane(vA23, k + 32);
            int lo = (q & 1) ? i1 : i0;
            int hi = (q & 1) ? i3 : i2;
            idxv[kk] = (q >= 2) ? hi : lo;
        }
        uint2 vals[16];
        #pragma unroll
        for (int kk = 0; kk < 16; ++kk)
            vals[kk] = *(const uint2*)(Pb + ((size_t)idxv[kk] << 6) + l15 * 4);
        #pragma unroll
        for (int kk = 0; kk < 16; ++kk) {
            uint2 v = vals[kk];
            m0 = fmaxf(m0, bf_lo(v.x)); m1 = fmaxf(m1, bf_hi(v.x));
            m2 = fmaxf(m2, bf_lo(v.y)); m3 = fmaxf(m3, bf_hi(v.y));
        }
    }
    {
        uint2 sv = *(const uint2*)(Pb + ((size_t)(n0 + wv * 4 + q) << 6) + l15 * 4);
        unsigned plo = pack2(m0 - bf_lo(sv.x), m1 - bf_hi(sv.x));
        unsigned phi = pack2(m2 - bf_lo(sv.y), m3 - bf_hi(sv.y));
        uint2 pk; pk.x = plo; pk.y = phi;
        *(uint2*)&feat_sh[(wv * 4 + q) * SW + l15 * 4] = pk;
    }
    __syncthreads();

    // ---- B fragments (identity layout): B[k][j] = w_ih[j][k]
    short8 bfrag[4][2];
    #pragma unroll
    for (int tt2 = 0; tt2 < 4; ++tt2) {
        int j = wv * 64 + tt2 * 16 + l15;
        #pragma unroll
        for (int ks = 0; ks < 2; ++ks) {
            int k0 = ks * 32 + q * 8;
            float4 w0 = *(const float4*)(w_ih + (size_t)j * OO + k0);
            float4 w1 = *(const float4*)(w_ih + (size_t)j * OO + k0 + 4);
            short8 bf;
            bf[0] = f2bs(w0.x); bf[1] = f2bs(w0.y);
            bf[2] = f2bs(w0.z); bf[3] = f2bs(w0.w);
            bf[4] = f2bs(w1.x); bf[5] = f2bs(w1.y);
            bf[6] = f2bs(w1.z); bf[7] = f2bs(w1.w);
            bfrag[tt2][ks] = bf;
        }
    }

    float4v acc[4] = {{0.f, 0.f, 0.f, 0.f}, {0.f, 0.f, 0.f, 0.f},
                      {0.f, 0.f, 0.f, 0.f}, {0.f, 0.f, 0.f, 0.f}};
    #pragma unroll
    for (int ks = 0; ks < 2; ++ks) {
        short8 af = *(const short8*)(&feat_sh[l15 * SW + ks * 32 + q * 8]);
        #pragma unroll
        for (int tt2 = 0; tt2 < 4; ++tt2)
            acc[tt2] = __builtin_amdgcn_mfma_f32_16x16x32_bf16(
                af, bfrag[tt2][ks], acc[tt2], 0, 0, 0);
    }

    // D: row m = q*4+rg, col j = wv*64 + tt*16 + l15
    #pragma unroll
    for (int tt2 = 0; tt2 < 4; ++tt2) {
        int j = wv * 64 + tt2 * 16 + l15;
        float bv = bias_sh[j];
        #pragma unroll
        for (int rg = 0; rg < 4; ++rg)
            gx[((size_t)(r0 + q * 4 + rg) << 8) + j] =
                __float2bfloat16(acc[tt2][rg] + bv);
    }
}

// Serial recurrence via MFMA: 16 agents/block (128 blocks). Wave w computes
// gate-plane w: D[agent][ch] = h @ w_hh[w*64+ch][:]^T  (8 MFMA/step, B-frags
// in regs, A-frag = 2 ds_read_b128 of bf16 h).  Gate exchange through small
// LDS planes; pointwise thread owns (agent, 4 ch), c in registers.
// Replaces R3's LDS-port-bound broadcast version (~32 b128/wave/step).
__global__ __launch_bounds__(256, 4) void lstm_kernel(
    const __hip_bfloat16* __restrict__ gx, const float* __restrict__ w_hh,
    float* __restrict__ out)
{
    const int tid = threadIdx.x;
    const int lane = tid & 63;
    const int wv = tid >> 6;          // gate plane
    const int l15 = lane & 15;
    const int q = lane >> 4;
    const int a0 = blockIdx.x * 16;
    const int a = tid >> 4;           // pointwise: agent
    const int c0 = (tid & 15) * 4;    // pointwise: first channel

    // B-frags: B[k][ch] = w_hh[wv*64 + ch][k]
    short8 bfrag[4][2];
    #pragma unroll
    for (int tt2 = 0; tt2 < 4; ++tt2) {
        int row = wv * 64 + tt2 * 16 + l15;
        #pragma unroll
        for (int ks = 0; ks < 2; ++ks) {
            int k0 = ks * 32 + q * 8;
            float4 w0 = *(const float4*)(w_hh + (size_t)row * OO + k0);
            float4 w1 = *(const float4*)(w_hh + (size_t)row * OO + k0 + 4);
            short8 bf;
            bf[0] = f2bs(w0.x); bf[1] = f2bs(w0.y);
            bf[2] = f2bs(w0.z); bf[3] = f2bs(w0.w);
            bf[4] = f2bs(w1.x); bf[5] = f2bs(w1.y);
            bf[6] = f2bs(w1.z); bf[7] = f2bs(w1.w);
            bfrag[tt2][ks] = bf;
        }
    }

    __shared__ __align__(16) unsigned short h_sh[16 * 72];  // bf16, pad 72
    __shared__ float gp[4][16][68];                         // gate planes

    {   // h = 0
        uint2 z; z.x = 0u; z.y = 0u;
        *(uint2*)&h_sh[a * 72 + c0] = z;
    }
    float cst[4] = {0.f, 0.f, 0.f, 0.f};

    const unsigned short* gxp = (const unsigned short*)gx;
    uint2 gxv[4];
    #pragma unroll
    for (int g = 0; g < 4; ++g)
        gxv[g] = *(const uint2*)(gxp + ((size_t)(a0 + a) << 8) + g * 64 + c0);

    for (int t = 0; t < TT; ++t) {
        __syncthreads();  // h_sh ready (init or previous pointwise)

        float4v acc[4] = {{0.f, 0.f, 0.f, 0.f}, {0.f, 0.f, 0.f, 0.f},
                          {0.f, 0.f, 0.f, 0.f}, {0.f, 0.f, 0.f, 0.f}};
        #pragma unroll
        for (int ks = 0; ks < 2; ++ks) {
            short8 af = *(const short8*)(&h_sh[l15 * 72 + ks * 32 + q * 8]);
            #pragma unroll
            for (int tt2 = 0; tt2 < 4; ++tt2)
                acc[tt2] = __builtin_amdgcn_mfma_f32_16x16x32_bf16(
                    af, bfrag[tt2][ks], acc[tt2], 0, 0, 0);
        }
        #pragma unroll
        for (int tt2 = 0; tt2 < 4; ++tt2)
            #pragma unroll
            for (int rg = 0; rg < 4; ++rg)
                gp[wv][q * 4 + rg][tt2 * 16 + l15] = acc[tt2][rg];

        // prefetch next step's gx while gp settles
        uint2 gxn[4];
        int tn = (t + 1 < TT) ? t + 1 : t;
        #pragma unroll
        for (int g = 0; g < 4; ++g)
            gxn[g] = *(const uint2*)(gxp + (((size_t)tn << 11) + a0 + a) * GG
                                     + g * 64 + c0);
        __syncthreads();  // gp ready

        float4 gv0 = *(const float4*)&gp[0][a][c0];
        float4 gv1 = *(const float4*)&gp[1][a][c0];
        float4 gv2 = *(const float4*)&gp[2][a][c0];
        float4 gv3 = *(const float4*)&gp[3][a][c0];
        float hv[4];
        {
            float gi[4] = {gv0.x + bf_lo(gxv[0].x), gv0.y + bf_hi(gxv[0].x),
                           gv0.z + bf_lo(gxv[0].y), gv0.w + bf_hi(gxv[0].y)};
            float gf[4] = {gv1.x + bf_lo(gxv[1].x), gv1.y + bf_hi(gxv[1].x),
                           gv1.z + bf_lo(gxv[1].y), gv1.w + bf_hi(gxv[1].y)};
            float gz[4] = {gv2.x + bf_lo(gxv[2].x), gv2.y + bf_hi(gxv[2].x),
                           gv2.z + bf_lo(gxv[2].y), gv2.w + bf_hi(gxv[2].y)};
            float go[4] = {gv3.x + bf_lo(gxv[3].x), gv3.y + bf_hi(gxv[3].x),
                           gv3.z + bf_lo(gxv[3].y), gv3.w + bf_hi(gxv[3].y)};
            #pragma unroll
            for (int e = 0; e < 4; ++e) {
                float ig = sigm(gi[e]);
                float fg = sigm(gf[e]);
                float zg = tanh_fast(gz[e]);
                float og = sigm(go[e]);
                cst[e] = fmaf(fg, cst[e], ig * zg);
                hv[e] = og * tanh_fast(cst[e]);
            }
        }
        {
            uint2 pk;
            pk.x = pack2(hv[0], hv[1]);
            pk.y = pack2(hv[2], hv[3]);
            *(uint2*)&h_sh[a * 72 + c0] = pk;
        }
        float4 ho; ho.x = hv[0]; ho.y = hv[1]; ho.z = hv[2]; ho.w = hv[3];
        *(float4*)(out + (((size_t)(a0 + a) * TT + t) << 6) + c0) = ho;
        if (t == TT - 1) {
            size_t hb = (size_t)NA * TT * OO;
            *(float4*)(out + hb + ((size_t)(a0 + a) << 6) + c0) = ho;
            float4 co; co.x = cst[0]; co.y = cst[1]; co.z = cst[2]; co.w = cst[3];
            *(float4*)(out + hb + ((size_t)NA << 6) + ((size_t)(a0 + a) << 6) + c0) = co;
        }
        gxv[0] = gxn[0]; gxv[1] = gxn[1]; gxv[2] = gxn[2]; gxv[3] = gxn[3];
    }
}

extern "C" void kernel_launch(void* const* d_in, const int* in_sizes, int n_in,
                              void* d_out, int out_size, void* d_ws, size_t ws_size,
                              hipStream_t stream) {
    const float* x      = (const float*)d_in[0];
    const int*   A      = (const int*)  d_in[1];
    const float* conv_w = (const float*)d_in[2];
    const float* conv_b = (const float*)d_in[3];
    const float* w_ih   = (const float*)d_in[4];
    const float* w_hh   = (const float*)d_in[5];
    const float* b_ih   = (const float*)d_in[6];
    const float* b_hh   = (const float*)d_in[7];
    float* out = (float*)d_out;

    __hip_bfloat16* P = (__hip_bfloat16*)d_ws;                       // 5.25 MB
    __hip_bfloat16* gx =
        (__hip_bfloat16*)((char*)d_ws + (size_t)TT * NA * OO * sizeof(__hip_bfloat16));  // 21 MB

    hipLaunchKernelGGL(proj_kernel, dim3(NA * TT / 16), dim3(256), 0, stream,
                       x, conv_w, P);
    hipLaunchKernelGGL(gatemm_kernel, dim3(NA * TT / 16), dim3(256), 0, stream,
                       P, A, conv_b, w_ih, b_ih, b_hh, gx);
    hipLaunchKernelGGL(lstm_kernel, dim3(NA / 16), dim3(256), 0, stream,
                       gx, w_hh, out);
}

// Round 5
// 157.304 us; speedup vs baseline: 1.2019x; 1.0365x over previous
//
#include <hip/hip_runtime.h>
#include <hip/hip_bf16.h>
#include <math.h>

#define NA 2048   // agents (2^11)
#define TT 20     // timesteps
#define KK 32     // neighbors
#define CC 32     // in channels
#define OO 64     // out channels / hidden
#define GG 256    // 4*OO gates
#define SW 88     // feat_sh row stride in shorts

typedef __attribute__((ext_vector_type(8))) short short8;
typedef __attribute__((ext_vector_type(4))) float float4v;
typedef __attribute__((ext_vector_type(4))) unsigned uint4v;

__device__ __forceinline__ float fast_rcp(float x) {
    return __builtin_amdgcn_rcpf(x);
}
__device__ __forceinline__ float sigm(float x) {
    return fast_rcp(1.f + __expf(-x));
}
__device__ __forceinline__ float tanh_fast(float x) {
    return 1.f - 2.f * fast_rcp(1.f + __expf(2.f * x));
}
__device__ __forceinline__ short f2bs(float f) {
    __hip_bfloat16 h = __float2bfloat16(f);
    short s;
    __builtin_memcpy(&s, &h, 2);
    return s;
}
__device__ __forceinline__ float bf_lo(unsigned u) {
    return __uint_as_float(u << 16);
}
__device__ __forceinline__ float bf_hi(unsigned u) {
    return __uint_as_float(u & 0xffff0000u);
}
__device__ __forceinline__ unsigned pack2(float a, float b) {
    return (unsigned)(unsigned short)f2bs(a) | ((unsigned)(unsigned short)f2bs(b) << 16);
}

// P[t][n][o] = sum_c x[n][t][c] * conv_w[o][c], stored bf16 (128B rows).
__global__ __launch_bounds__(256) void proj_kernel(
    const float* __restrict__ x, const float* __restrict__ conv_w,
    __hip_bfloat16* __restrict__ P)
{
    const int lane = threadIdx.x & 63;
    const int wv = threadIdx.x >> 6;
    float w[CC];
    #pragma unroll
    for (int c = 0; c < CC; c += 4) {
        float4 v = *(const float4*)(conv_w + lane * CC + c);
        w[c] = v.x; w[c + 1] = v.y; w[c + 2] = v.z; w[c + 3] = v.w;
    }
    const int rbase = blockIdx.x * 16 + wv * 4;
    #pragma unroll
    for (int i = 0; i < 4; ++i) {
        int r = rbase + i;                    // r = n*TT + t (x row order)
        const float* xr = x + (size_t)r * CC;
        float a0 = 0.f, a1 = 0.f;
        #pragma unroll
        for (int c = 0; c < CC; c += 8) {
            float4 v = *(const float4*)(xr + c);
            float4 u = *(const float4*)(xr + c + 4);
            a0 = fmaf(v.x, w[c], a0);     a0 = fmaf(v.y, w[c + 1], a0);
            a0 = fmaf(v.z, w[c + 2], a0); a0 = fmaf(v.w, w[c + 3], a0);
            a1 = fmaf(u.x, w[c + 4], a1); a1 = fmaf(u.y, w[c + 5], a1);
            a1 = fmaf(u.z, w[c + 6], a1); a1 = fmaf(u.w, w[c + 7], a1);
        }
        int n = r / TT;
        int t = r - n * TT;
        P[(((size_t)t << 11) + n) * OO + lane] = __float2bfloat16(a0 + a1);
    }
}

// Gather-max + gate matmul (MFMA).
// R4 was latency-bound: compiler (VGPR=36) re-fused loads with consumption,
// ~2 loads/wave in flight. Here each lane issues 16 INDEPENDENT dwordx4
// P-loads, pinned before consumption by asm memory barriers (loads cannot
// sink past a memory clobber) -> back-to-back issue, per-use vmcnt.
// Lane layout: i_row = lane>>4 (wave's 4 rows), ko2 = neighbor parity,
// oc = channel oct. Cross-lane max = one shfl_xor(8).
__global__ __launch_bounds__(256, 3) void gatemm_kernel(
    const __hip_bfloat16* __restrict__ P, const int* __restrict__ A,
    const float* __restrict__ conv_b, const float* __restrict__ w_ih,
    const float* __restrict__ b_ih, const float* __restrict__ b_hh,
    __hip_bfloat16* __restrict__ gx)
{
    const int tid = threadIdx.x;
    const int lane = tid & 63;
    const int wv = tid >> 6;
    const int l15 = lane & 15;
    const int q = lane >> 4;

    const int bs = (blockIdx.x & 7) * 320 + (blockIdx.x >> 3);  // XCD swizzle
    const int r0 = bs << 4;                  // first row, r = t*NA + n
    const int t = r0 >> 11;
    const int n0 = r0 & (NA - 1);
    const unsigned short* Pb = (const unsigned short*)P + ((size_t)t << 17);

    __shared__ float bias_sh[GG];
    __shared__ __align__(16) unsigned short feat_sh[16 * SW];

    // bias for gate-row tid (conv_b folded through w_ih)
    {
        float bj = b_ih[tid] + b_hh[tid];
        #pragma unroll
        for (int o = 0; o < OO; o += 4) {
            float4 cb = *(const float4*)(conv_b + o);
            float4 wr = *(const float4*)(w_ih + (size_t)tid * OO + o);
            bj = fmaf(cb.x, wr.x, bj); bj = fmaf(cb.y, wr.y, bj);
            bj = fmaf(cb.z, wr.z, bj); bj = fmaf(cb.w, wr.w, bj);
        }
        bias_sh[tid] = bj;
    }

    // ---- gather-max ----
    const int i_row = lane >> 4;        // 0..3: which of the wave's 4 rows
    const int ko2   = (lane >> 3) & 1;  // neighbor parity
    const int oc    = lane & 7;         // channel oct (8 bf16 = 16B)

    const int myrow = r0 + wv * 4 + i_row;
    const int* aRow = A + ((size_t)myrow << 5) + ko2;

    // batch 1: 16 A-index loads + self row (independent)
    int ai[16];
    #pragma unroll
    for (int g = 0; g < 16; ++g) ai[g] = aRow[g * 2];   // k = 2g + ko2
    uint4v sv = *(const uint4v*)(Pb + ((size_t)(n0 + wv * 4 + i_row) << 6) + oc * 8);
    asm volatile("" ::: "memory");   // pin batch-1 issue before use

    // batch 2: 16 gathered P loads (dwordx4 each), all independent
    uint4v pv[16];
    #pragma unroll
    for (int g = 0; g < 16; ++g)
        pv[g] = *(const uint4v*)(Pb + ((size_t)ai[g] << 6) + oc * 8);
    asm volatile("" ::: "memory");   // pin batch-2 issue before reduction

    float mx[8];
    #pragma unroll
    for (int e = 0; e < 8; ++e) mx[e] = -INFINITY;
    #pragma unroll
    for (int g = 0; g < 16; ++g) {
        uint4v v = pv[g];
        mx[0] = fmaxf(mx[0], bf_lo(v[0])); mx[1] = fmaxf(mx[1], bf_hi(v[0]));
        mx[2] = fmaxf(mx[2], bf_lo(v[1])); mx[3] = fmaxf(mx[3], bf_hi(v[1]));
        mx[4] = fmaxf(mx[4], bf_lo(v[2])); mx[5] = fmaxf(mx[5], bf_hi(v[2]));
        mx[6] = fmaxf(mx[6], bf_lo(v[3])); mx[7] = fmaxf(mx[7], bf_hi(v[3]));
    }
    #pragma unroll
    for (int e = 0; e < 8; ++e)
        mx[e] = fmaxf(mx[e], __shfl_xor(mx[e], 8, 64));  // combine parities

    if (ko2 == 0) {   // 32 lanes write: row m = wv*4+i_row, shorts oc*8..+8
        uint4v pk;
        pk[0] = pack2(mx[0] - bf_lo(sv[0]), mx[1] - bf_hi(sv[0]));
        pk[1] = pack2(mx[2] - bf_lo(sv[1]), mx[3] - bf_hi(sv[1]));
        pk[2] = pack2(mx[4] - bf_lo(sv[2]), mx[5] - bf_hi(sv[2]));
        pk[3] = pack2(mx[6] - bf_lo(sv[3]), mx[7] - bf_hi(sv[3]));
        *(uint4v*)&feat_sh[(wv * 4 + i_row) * SW + oc * 8] = pk;
    }
    __syncthreads();

    // ---- B fragments (identity layout): B[k][j] = w_ih[j][k]
    short8 bfrag[4][2];
    #pragma unroll
    for (int tt2 = 0; tt2 < 4; ++tt2) {
        int j = wv * 64 + tt2 * 16 + l15;
        #pragma unroll
        for (int ks = 0; ks < 2; ++ks) {
            int k0 = ks * 32 + q * 8;
            float4 w0 = *(const float4*)(w_ih + (size_t)j * OO + k0);
            float4 w1 = *(const float4*)(w_ih + (size_t)j * OO + k0 + 4);
            short8 bf;
            bf[0] = f2bs(w0.x); bf[1] = f2bs(w0.y);
            bf[2] = f2bs(w0.z); bf[3] = f2bs(w0.w);
            bf[4] = f2bs(w1.x); bf[5] = f2bs(w1.y);
            bf[6] = f2bs(w1.z); bf[7] = f2bs(w1.w);
            bfrag[tt2][ks] = bf;
        }
    }

    float4v acc[4] = {{0.f, 0.f, 0.f, 0.f}, {0.f, 0.f, 0.f, 0.f},
                      {0.f, 0.f, 0.f, 0.f}, {0.f, 0.f, 0.f, 0.f}};
    #pragma unroll
    for (int ks = 0; ks < 2; ++ks) {
        short8 af = *(const short8*)(&feat_sh[l15 * SW + ks * 32 + q * 8]);
        #pragma unroll
        for (int tt2 = 0; tt2 < 4; ++tt2)
            acc[tt2] = __builtin_amdgcn_mfma_f32_16x16x32_bf16(
                af, bfrag[tt2][ks], acc[tt2], 0, 0, 0);
    }

    // D: row m = q*4+rg, col j = wv*64 + tt2*16 + l15
    #pragma unroll
    for (int tt2 = 0; tt2 < 4; ++tt2) {
        int j = wv * 64 + tt2 * 16 + l15;
        float bv = bias_sh[j];
        #pragma unroll
        for (int rg = 0; rg < 4; ++rg)
            gx[((size_t)(r0 + q * 4 + rg) << 8) + j] =
                __float2bfloat16(acc[tt2][rg] + bv);
    }
}

// Serial recurrence via MFMA: 16 agents/block (128 blocks). Wave w computes
// gate-plane w: D[agent][ch] = h @ w_hh[w*64+ch][:]^T  (8 MFMA/step, B-frags
// in regs, A-frag = 2 ds_read_b128 of bf16 h).  Gate exchange through small
// LDS planes; pointwise thread owns (agent, 4 ch), c in registers.
__global__ __launch_bounds__(256, 4) void lstm_kernel(
    const __hip_bfloat16* __restrict__ gx, const float* __restrict__ w_hh,
    float* __restrict__ out)
{
    const int tid = threadIdx.x;
    const int lane = tid & 63;
    const int wv = tid >> 6;          // gate plane
    const int l15 = lane & 15;
    const int q = lane >> 4;
    const int a0 = blockIdx.x * 16;
    const int a = tid >> 4;           // pointwise: agent
    const int c0 = (tid & 15) * 4;    // pointwise: first channel

    // B-frags: B[k][ch] = w_hh[wv*64 + ch][k]
    short8 bfrag[4][2];
    #pragma unroll
    for (int tt2 = 0; tt2 < 4; ++tt2) {
        int row = wv * 64 + tt2 * 16 + l15;
        #pragma unroll
        for (int ks = 0; ks < 2; ++ks) {
            int k0 = ks * 32 + q * 8;
            float4 w0 = *(const float4*)(w_hh + (size_t)row * OO + k0);
            float4 w1 = *(const float4*)(w_hh + (size_t)row * OO + k0 + 4);
            short8 bf;
            bf[0] = f2bs(w0.x); bf[1] = f2bs(w0.y);
            bf[2] = f2bs(w0.z); bf[3] = f2bs(w0.w);
            bf[4] = f2bs(w1.x); bf[5] = f2bs(w1.y);
            bf[6] = f2bs(w1.z); bf[7] = f2bs(w1.w);
            bfrag[tt2][ks] = bf;
        }
    }

    __shared__ __align__(16) unsigned short h_sh[16 * 72];  // bf16, pad 72
    __shared__ float gp[4][16][68];                         // gate planes

    {   // h = 0
        uint2 z; z.x = 0u; z.y = 0u;
        *(uint2*)&h_sh[a * 72 + c0] = z;
    }
    float cst[4] = {0.f, 0.f, 0.f, 0.f};

    const unsigned short* gxp = (const unsigned short*)gx;
    uint2 gxv[4];
    #pragma unroll
    for (int g = 0; g < 4; ++g)
        gxv[g] = *(const uint2*)(gxp + ((size_t)(a0 + a) << 8) + g * 64 + c0);

    for (int t = 0; t < TT; ++t) {
        __syncthreads();  // h_sh ready (init or previous pointwise)

        float4v acc[4] = {{0.f, 0.f, 0.f, 0.f}, {0.f, 0.f, 0.f, 0.f},
                          {0.f, 0.f, 0.f, 0.f}, {0.f, 0.f, 0.f, 0.f}};
        #pragma unroll
        for (int ks = 0; ks < 2; ++ks) {
            short8 af = *(const short8*)(&h_sh[l15 * 72 + ks * 32 + q * 8]);
            #pragma unroll
            for (int tt2 = 0; tt2 < 4; ++tt2)
                acc[tt2] = __builtin_amdgcn_mfma_f32_16x16x32_bf16(
                    af, bfrag[tt2][ks], acc[tt2], 0, 0, 0);
        }
        #pragma unroll
        for (int tt2 = 0; tt2 < 4; ++tt2)
            #pragma unroll
            for (int rg = 0; rg < 4; ++rg)
                gp[wv][q * 4 + rg][tt2 * 16 + l15] = acc[tt2][rg];

        // prefetch next step's gx while gp settles
        uint2 gxn[4];
        int tn = (t + 1 < TT) ? t + 1 : t;
        #pragma unroll
        for (int g = 0; g < 4; ++g)
            gxn[g] = *(const uint2*)(gxp + (((size_t)tn << 11) + a0 + a) * GG
                                     + g * 64 + c0);
        __syncthreads();  // gp ready

        float4 gv0 = *(const float4*)&gp[0][a][c0];
        float4 gv1 = *(const float4*)&gp[1][a][c0];
        float4 gv2 = *(const float4*)&gp[2][a][c0];
        float4 gv3 = *(const float4*)&gp[3][a][c0];
        float hv[4];
        {
            float gi[4] = {gv0.x + bf_lo(gxv[0].x), gv0.y + bf_hi(gxv[0].x),
                           gv0.z + bf_lo(gxv[0].y), gv0.w + bf_hi(gxv[0].y)};
            float gf[4] = {gv1.x + bf_lo(gxv[1].x), gv1.y + bf_hi(gxv[1].x),
                           gv1.z + bf_lo(gxv[1].y), gv1.w + bf_hi(gxv[1].y)};
            float gz[4] = {gv2.x + bf_lo(gxv[2].x), gv2.y + bf_hi(gxv[2].x),
                           gv2.z + bf_lo(gxv[2].y), gv2.w + bf_hi(gxv[2].y)};
            float go[4] = {gv3.x + bf_lo(gxv[3].x), gv3.y + bf_hi(gxv[3].x),
                           gv3.z + bf_lo(gxv[3].y), gv3.w + bf_hi(gxv[3].y)};
            #pragma unroll
            for (int e = 0; e < 4; ++e) {
                float ig = sigm(gi[e]);
                float fg = sigm(gf[e]);
                float zg = tanh_fast(gz[e]);
                float og = sigm(go[e]);
                cst[e] = fmaf(fg, cst[e], ig * zg);
                hv[e] = og * tanh_fast(cst[e]);
            }
        }
        {
            uint2 pk;
            pk.x = pack2(hv[0], hv[1]);
            pk.y = pack2(hv[2], hv[3]);
            *(uint2*)&h_sh[a * 72 + c0] = pk;
        }
        float4 ho; ho.x = hv[0]; ho.y = hv[1]; ho.z = hv[2]; ho.w = hv[3];
        *(float4*)(out + (((size_t)(a0 + a) * TT + t) << 6) + c0) = ho;
        if (t == TT - 1) {
            size_t hb = (size_t)NA * TT * OO;
            *(float4*)(out + hb + ((size_t)(a0 + a) << 6) + c0) = ho;
            float4 co; co.x = cst[0]; co.y = cst[1]; co.z = cst[2]; co.w = cst[3];
            *(float4*)(out + hb + ((size_t)NA << 6) + ((size_t)(a0 + a) << 6) + c0) = co;
        }
        gxv[0] = gxn[0]; gxv[1] = gxn[1]; gxv[2] = gxn[2]; gxv[3] = gxn[3];
    }
}

extern "C" void kernel_launch(void* const* d_in, const int* in_sizes, int n_in,
                              void* d_out, int out_size, void* d_ws, size_t ws_size,
                              hipStream_t stream) {
    const float* x      = (const float*)d_in[0];
    const int*   A      = (const int*)  d_in[1];
    const float* conv_w = (const float*)d_in[2];
    const float* conv_b = (const float*)d_in[3];
    const float* w_ih   = (const float*)d_in[4];
    const float* w_hh   = (const float*)d_in[5];
    const float* b_ih   = (const float*)d_in[6];
    const float* b_hh   = (const float*)d_in[7];
    float* out = (float*)d_out;

    __hip_bfloat16* P = (__hip_bfloat16*)d_ws;                       // 5.25 MB
    __hip_bfloat16* gx =
        (__hip_bfloat16*)((char*)d_ws + (size_t)TT * NA * OO * sizeof(__hip_bfloat16));  // 21 MB

    hipLaunchKernelGGL(proj_kernel, dim3(NA * TT / 16), dim3(256), 0, stream,
                       x, conv_w, P);
    hipLaunchKernelGGL(gatemm_kernel, dim3(NA * TT / 16), dim3(256), 0, stream,
                       P, A, conv_b, w_ih, b_ih, b_hh, gx);
    hipLaunchKernelGGL(lstm_kernel, dim3(NA / 16), dim3(256), 0, stream,
                       gx, w_hh, out);
}